// Round 12
// baseline (153.096 us; speedup 1.0000x reference)
//
#include <hip/hip_runtime.h>
#include <math.h>

// B=4, T=4096, C=1024, H=64. fp32 in/out, bf16 MFMA internally.
// K1 wtrans: W (C,H) fp32 -> WT bf16 [192][1024].
// K2 qkv_proj: BARRIER-FREE. 256 thr = 4 independent waves; wave nq computes
//              n-tiles 3nq..3nq+2 for BOTH 16-row m-tiles. WT slice (rows
//              48nq..48nq+47) is WAVE-PRIVATE -> single-buffer LDS staged and
//              read by the same wave (in-order DS, no syncthreads). x A-frags
//              load DIRECTLY from global (2 float4/frag, f2bf in-reg), 1-iter
//              lookahead; x redundancy x4 within block is L1/L2-absorbed.
//              27.6 KB LDS, 4 blocks/CU -> 16 waves/CU, zero convoy.
//              MFMA k-order identical to r7 -> bitwise-identical outputs.
// K3 attn: r7-exact (best measured 138.4): software-pipelined, QK(kt+1)+PV(kt)
//          fused MFMA cluster, softmax under PV, reg-staged us8 dbuf, swapped
//          mfma(K,Q), in-register P transpose (cvt_pk+permlane), ones-frag l.
// K4 reduce_norm: per row, sum ceil((qt+1)/8) slabs, out = O_sum / l_sum.

#define BT   16384
#define TDIM 4096
#define CDIM 1024
#define HDIM 64
#define ACCW 68           // slab row stride (floats); col 64 holds l
#define NSLOT 288         // chunk slots per batch (chunk = 8 kv-tiles)

typedef __attribute__((ext_vector_type(8))) short bf16x8;
typedef __attribute__((ext_vector_type(4))) float f32x4;
typedef __attribute__((ext_vector_type(8))) unsigned short us8;
typedef __attribute__((ext_vector_type(4))) unsigned short us4;

static __device__ __forceinline__ unsigned short f2bf(float f) {
    unsigned int u = __float_as_uint(f);
    u += 0x7fffu + ((u >> 16) & 1u);
    return (unsigned short)(u >> 16);
}

static __device__ __forceinline__ bf16x8 pack8(float4 lo, float4 hi) {
    us8 r = { f2bf(lo.x), f2bf(lo.y), f2bf(lo.z), f2bf(lo.w),
              f2bf(hi.x), f2bf(hi.y), f2bf(hi.z), f2bf(hi.w) };
    union { us8 u; bf16x8 v; } c; c.u = r; return c.v;
}

// Chained lane-swap: after pswap(x,y),
//   x = [X(q0), X(q2), Y(q0), Y(q2)] per quad, y = [X(q1), X(q3), Y(q1), Y(q3)]
// = A-frag words w / w+2 when X=c[st_lo][h], Y=c[st_hi][h].
static __device__ __forceinline__ void pswap(unsigned &x, unsigned &y) {
    asm("v_permlane32_swap_b32 %0, %1" : "+v"(x), "+v"(y));
    asm("v_permlane16_swap_b32 %0, %1" : "+v"(x), "+v"(y));
}

// p = exp(sT) (+ diagonal causal mask), packed into the PV A-fragment layout.
static __device__ __forceinline__ void softmax_pack(
    const f32x4 sT[4], bool diag, int qloc, int quad,
    bf16x8 &pa0, bf16x8 &pa1)
{
    float p[4][4];
    if (diag) {
        #pragma unroll
        for (int st = 0; st < 4; st++)
            #pragma unroll
            for (int r = 0; r < 4; r++) {
                int kkloc = st * 16 + quad * 4 + r;
                p[st][r] = (kkloc > qloc) ? 0.f : __expf(sT[st][r]);
            }
    } else {
        #pragma unroll
        for (int st = 0; st < 4; st++)
            #pragma unroll
            for (int r = 0; r < 4; r++)
                p[st][r] = __expf(sT[st][r]);
    }
    unsigned cpk[4][2];
    #pragma unroll
    for (int st = 0; st < 4; st++) {
        asm("v_cvt_pk_bf16_f32 %0, %1, %2"
            : "=v"(cpk[st][0]) : "v"(p[st][0]), "v"(p[st][1]));
        asm("v_cvt_pk_bf16_f32 %0, %1, %2"
            : "=v"(cpk[st][1]) : "v"(p[st][2]), "v"(p[st][3]));
    }
    union { unsigned u[4]; bf16x8 v; } u0, u1;
    unsigned a0 = cpk[0][0], b0 = cpk[1][0]; pswap(a0, b0);
    unsigned a1 = cpk[0][1], b1 = cpk[1][1]; pswap(a1, b1);
    u0.u[0] = a0; u0.u[1] = a1; u0.u[2] = b0; u0.u[3] = b1;
    unsigned a2 = cpk[2][0], b2 = cpk[3][0]; pswap(a2, b2);
    unsigned a3 = cpk[2][1], b3 = cpk[3][1]; pswap(a3, b3);
    u1.u[0] = a2; u1.u[1] = a3; u1.u[2] = b2; u1.u[3] = b3;
    pa0 = u0.v; pa1 = u1.v;
}

// ---------------- K1: W transpose->bf16 ----------------
__global__ __launch_bounds__(256) void wtrans(
    const float* __restrict__ Wk, const float* __restrict__ Wq,
    const float* __restrict__ Wv, unsigned short* __restrict__ wtg)
{
    int idx = blockIdx.x * 256 + threadIdx.x;     // 0..196607
    int mat = idx >> 16;
    int rem = idx & 65535;
    int h = rem >> 10, c = rem & 1023;
    const float* W = (mat == 0) ? Wk : (mat == 1) ? Wq : Wv;
    wtg[idx] = f2bf(W[c * HDIM + h]);             // WT[mat*64+h][c]
}

// ---------------- K2: barrier-free QKV projection ----------------
__global__ __launch_bounds__(256) void qkv_proj(
    const float* __restrict__ x, const unsigned short* __restrict__ wtg,
    unsigned short* __restrict__ kg, unsigned short* __restrict__ qg,
    unsigned short* __restrict__ vtg)
{
    __shared__ __align__(16) unsigned short wts[192][72];   // 27.6 KB, wave-sliced
    const int t = threadIdx.x;
    const int lane = t & 63, wv = t >> 6, quad = lane >> 4, l16 = lane & 15;
    const int row0 = blockIdx.x * 32;

    // WT staging: wave wv owns rows 48wv..48wv+47; 6 us8 per lane per chunk
    const int wrb = wv * 48 + (lane >> 3);       // +d*8, d=0..5
    const int wc8 = (lane & 7) * 8;

    // x A-fragment global base: lane reads x[row0 + mt*16 + l16][cc + kh*32 + quad*8]
    const size_t xr0 = (size_t)(row0 + l16) * CDIM + quad * 8;        // mt=0
    const size_t xr1 = xr0 + (size_t)16 * CDIM;                        // mt=1

    f32x4 acc[2][3];
    #pragma unroll
    for (int m = 0; m < 2; m++)
        #pragma unroll
        for (int j = 0; j < 3; j++) acc[m][j] = (f32x4){0.f, 0.f, 0.f, 0.f};

    // prologue: chunk 0 into regs
    us8 w[6];
    #pragma unroll
    for (int d = 0; d < 6; d++)
        w[d] = *(const us8*)&wtg[(size_t)(wrb + d * 8) * CDIM + wc8];
    float4 xf[8];                                  // [mt*4 + kh*2 + half]
    #pragma unroll
    for (int mt = 0; mt < 2; mt++)
        #pragma unroll
        for (int kh = 0; kh < 2; kh++) {
            const size_t base = (mt ? xr1 : xr0) + kh * 32;
            xf[mt * 4 + kh * 2 + 0] = *(const float4*)&x[base];
            xf[mt * 4 + kh * 2 + 1] = *(const float4*)&x[base + 4];
        }

    #pragma unroll
    for (int it = 0; it < 16; it++) {
        // stage WT chunk it into this wave's private slice (in-order DS: the
        // previous iteration's ds_reads precede these writes in program order)
        #pragma unroll
        for (int d = 0; d < 6; d++)
            *(us8*)&wts[wrb + d * 8][wc8] = w[d];

        // pack this chunk's A-fragments from registers
        bf16x8 a[2][2];
        #pragma unroll
        for (int mt = 0; mt < 2; mt++)
            #pragma unroll
            for (int kh = 0; kh < 2; kh++)
                a[mt][kh] = pack8(xf[mt * 4 + kh * 2], xf[mt * 4 + kh * 2 + 1]);

        // preload chunk it+1 into regs (WT + x), 1 iteration of lookahead
        if (it + 1 < 16) {
            const int nc = (it + 1) * 64;
            #pragma unroll
            for (int d = 0; d < 6; d++)
                w[d] = *(const us8*)&wtg[(size_t)(wrb + d * 8) * CDIM + nc + wc8];
            #pragma unroll
            for (int mt = 0; mt < 2; mt++)
                #pragma unroll
                for (int kh = 0; kh < 2; kh++) {
                    const size_t base = (mt ? xr1 : xr0) + nc + kh * 32;
                    xf[mt * 4 + kh * 2 + 0] = *(const float4*)&x[base];
                    xf[mt * 4 + kh * 2 + 1] = *(const float4*)&x[base + 4];
                }
        }

        // compute: B-frags from this wave's slice; MFMA k-order = r7's
        #pragma unroll
        for (int j = 0; j < 3; j++) {
            const int nt = wv * 3 + j;
            bf16x8 b0 = *(const bf16x8*)&wts[nt * 16 + l16][quad * 8];
            bf16x8 b1 = *(const bf16x8*)&wts[nt * 16 + l16][32 + quad * 8];
            acc[0][j] = __builtin_amdgcn_mfma_f32_16x16x32_bf16(a[0][0], b0, acc[0][j], 0, 0, 0);
            acc[0][j] = __builtin_amdgcn_mfma_f32_16x16x32_bf16(a[0][1], b1, acc[0][j], 0, 0, 0);
            acc[1][j] = __builtin_amdgcn_mfma_f32_16x16x32_bf16(a[1][0], b0, acc[1][j], 0, 0, 0);
            acc[1][j] = __builtin_amdgcn_mfma_f32_16x16x32_bf16(a[1][1], b1, acc[1][j], 0, 0, 0);
        }
    }

    #pragma unroll
    for (int mt = 0; mt < 2; mt++) {
        const int mrow = row0 + mt * 16 + quad * 4;
        #pragma unroll
        for (int j = 0; j < 3; j++) {
            int nt = wv * 3 + j;
            int mat = nt >> 2;
            int col = (nt & 3) * 16 + l16;
            if (mat == 2) {
                // V: 4 regs are 4 consecutive t at fixed h -> contiguous in vtg
                int bb = mrow >> 12, tr = mrow & 4095;  // rows never cross batch
                us4 pv = { f2bf(acc[mt][j][0]), f2bf(acc[mt][j][1]),
                           f2bf(acc[mt][j][2]), f2bf(acc[mt][j][3]) };
                *(us4*)&vtg[((size_t)(bb * HDIM + col) << 12) + tr] = pv;
            } else {
                // Q is pre-scaled by 1/8 (exact power-of-2 in bf16)
                float s = (mat == 1) ? 0.125f : 1.0f;
                unsigned short* dst = (mat == 0) ? kg : qg;
                #pragma unroll
                for (int reg = 0; reg < 4; reg++)
                    dst[(size_t)(mrow + reg) * HDIM + col] = f2bf(acc[mt][j][reg] * s);
            }
        }
    }
}

// ---------------- K3: software-pipelined flash attention (r7-exact) ---------
// slot layout per batch (chunk = 8 tiles): group a = qt>>3 has (a+1) chunks
// per qt; group a starts at slot 4a(a+1); qt's slots: base + (qt&7)*(a+1).
__global__ __launch_bounds__(256) void attn(
    const unsigned short* __restrict__ qg, const unsigned short* __restrict__ kg,
    const unsigned short* __restrict__ vtg, float* __restrict__ slabs)
{
    __shared__ __align__(16) unsigned short Ks[2][64][72];
    __shared__ __align__(16) unsigned short Vt[2][64][72];    // 36 KB total

    const int t = threadIdx.x;
    const int lane = t & 63, wv = t >> 6, quad = lane >> 4, l16 = lane & 15;

    const int b = blockIdx.x / NSLOT;
    const int s = blockIdx.x - b * NSLOT;
    int a;
    if      (s < 8)   a = 0;
    else if (s < 24)  a = 1;
    else if (s < 48)  a = 2;
    else if (s < 80)  a = 3;
    else if (s < 120) a = 4;
    else if (s < 168) a = 5;
    else if (s < 224) a = 6;
    else              a = 7;
    const int u  = s - 4 * a * (a + 1);
    const int qt = a * 8 + u / (a + 1);
    const int c  = u % (a + 1);

    const size_t bbase = (size_t)b * TDIM;
    const int Q0 = qt * 64;
    const int kt0 = c * 8;
    const int kt1 = (kt0 + 7 < qt) ? kt0 + 7 : qt;

    // Q fragments (B-operand of swapped QK^T: n=l16 is the q-row)
    const int qrow = Q0 + wv * 16 + l16;
    const bf16x8 qa0 = *(const bf16x8*)&qg[(bbase + qrow) * HDIM + quad * 8];
    const bf16x8 qa1 = *(const bf16x8*)&qg[(bbase + qrow) * HDIM + 32 + quad * 8];

    // l-row B-fragment: register constant (col 0 of virtual ones-row)
    const short onev = (l16 == 0) ? (short)0x3F80 : (short)0;
    const bf16x8 ones = { onev, onev, onev, onev, onev, onev, onev, onev };

    f32x4 O[5];
    #pragma unroll
    for (int i = 0; i < 5; i++) O[i] = (f32x4){0.f, 0.f, 0.f, 0.f};

    const int fr = t >> 3, fc = (t & 7) * 8;

    // prologue: tile kt0 -> buf 0; preload tile kt0+1 into regs
    us8 kr0 = *(const us8*)&kg[(bbase + kt0 * 64 + fr) * HDIM + fc];
    us8 kr1 = *(const us8*)&kg[(bbase + kt0 * 64 + fr + 32) * HDIM + fc];
    us8 vr0 = *(const us8*)&vtg[((size_t)(b * HDIM + fr) << 12) + kt0 * 64 + fc];
    us8 vr1 = *(const us8*)&vtg[((size_t)(b * HDIM + fr + 32) << 12) + kt0 * 64 + fc];
    *(us8*)&Ks[0][fr][fc] = kr0;
    *(us8*)&Ks[0][fr + 32][fc] = kr1;
    *(us8*)&Vt[0][fr][fc] = vr0;
    *(us8*)&Vt[0][fr + 32][fc] = vr1;
    if (kt0 < kt1) {
        int kn = kt0 + 1;
        kr0 = *(const us8*)&kg[(bbase + kn * 64 + fr) * HDIM + fc];
        kr1 = *(const us8*)&kg[(bbase + kn * 64 + fr + 32) * HDIM + fc];
        vr0 = *(const us8*)&vtg[((size_t)(b * HDIM + fr) << 12) + kn * 64 + fc];
        vr1 = *(const us8*)&vtg[((size_t)(b * HDIM + fr + 32) << 12) + kn * 64 + fc];
    }
    __syncthreads();

    const int qloc = wv * 16 + l16;        // this lane's q row, Q-tile-local

    // prologue compute: QK(kt0) + softmax(kt0) -> pa
    bf16x8 pa0, pa1;
    {
        f32x4 sT[4];
        #pragma unroll
        for (int st = 0; st < 4; st++) {
            bf16x8 kb0 = *(const bf16x8*)&Ks[0][st * 16 + l16][quad * 8];
            bf16x8 kb1 = *(const bf16x8*)&Ks[0][st * 16 + l16][32 + quad * 8];
            f32x4 z = (f32x4){0.f, 0.f, 0.f, 0.f};
            z = __builtin_amdgcn_mfma_f32_16x16x32_bf16(kb0, qa0, z, 0, 0, 0);
            z = __builtin_amdgcn_mfma_f32_16x16x32_bf16(kb1, qa1, z, 0, 0, 0);
            sT[st] = z;
        }
        softmax_pack(sT, kt0 == qt, qloc, quad, pa0, pa1);
    }

    int buf = 0;
    for (int kt = kt0; kt < kt1; ++kt) {
        // stage tile kt+1 (in regs) into buf^1; issue preload of kt+2
        *(us8*)&Ks[buf ^ 1][fr][fc] = kr0;
        *(us8*)&Ks[buf ^ 1][fr + 32][fc] = kr1;
        *(us8*)&Vt[buf ^ 1][fr][fc] = vr0;
        *(us8*)&Vt[buf ^ 1][fr + 32][fc] = vr1;
        if (kt + 2 <= kt1) {
            int kn = kt + 2;
            kr0 = *(const us8*)&kg[(bbase + kn * 64 + fr) * HDIM + fc];
            kr1 = *(const us8*)&kg[(bbase + kn * 64 + fr + 32) * HDIM + fc];
            vr0 = *(const us8*)&vtg[((size_t)(b * HDIM + fr) << 12) + kn * 64 + fc];
            vr1 = *(const us8*)&vtg[((size_t)(b * HDIM + fr + 32) << 12) + kn * 64 + fc];
        }
        __syncthreads();

        // QK(kt+1) from Ks[buf^1], then PV(kt) from Vt[buf]: 18 MFMA fused.
        __builtin_amdgcn_s_setprio(1);
        f32x4 sT[4];
        #pragma unroll
        for (int st = 0; st < 4; st++) {
            bf16x8 kb0 = *(const bf16x8*)&Ks[buf ^ 1][st * 16 + l16][quad * 8];
            bf16x8 kb1 = *(const bf16x8*)&Ks[buf ^ 1][st * 16 + l16][32 + quad * 8];
            f32x4 z = (f32x4){0.f, 0.f, 0.f, 0.f};
            z = __builtin_amdgcn_mfma_f32_16x16x32_bf16(kb0, qa0, z, 0, 0, 0);
            z = __builtin_amdgcn_mfma_f32_16x16x32_bf16(kb1, qa1, z, 0, 0, 0);
            sT[st] = z;
        }
        #pragma unroll
        for (int nt = 0; nt < 4; nt++) {
            bf16x8 vb0 = *(const bf16x8*)&Vt[buf][nt * 16 + l16][quad * 8];
            bf16x8 vb1 = *(const bf16x8*)&Vt[buf][nt * 16 + l16][32 + quad * 8];
            O[nt] = __builtin_amdgcn_mfma_f32_16x16x32_bf16(pa0, vb0, O[nt], 0, 0, 0);
            O[nt] = __builtin_amdgcn_mfma_f32_16x16x32_bf16(pa1, vb1, O[nt], 0, 0, 0);
        }
        O[4] = __builtin_amdgcn_mfma_f32_16x16x32_bf16(pa0, ones, O[4], 0, 0, 0);
        O[4] = __builtin_amdgcn_mfma_f32_16x16x32_bf16(pa1, ones, O[4], 0, 0, 0);
        __builtin_amdgcn_s_setprio(0);

        // softmax(kt+1): its QK dependence drains while PV occupies the pipe
        softmax_pack(sT, (kt + 1) == qt, qloc, quad, pa0, pa1);

        __syncthreads();
        buf ^= 1;
    }

    // epilogue: PV(kt1) from Vt[buf]
    #pragma unroll
    for (int nt = 0; nt < 4; nt++) {
        bf16x8 vb0 = *(const bf16x8*)&Vt[buf][nt * 16 + l16][quad * 8];
        bf16x8 vb1 = *(const bf16x8*)&Vt[buf][nt * 16 + l16][32 + quad * 8];
        O[nt] = __builtin_amdgcn_mfma_f32_16x16x32_bf16(pa0, vb0, O[nt], 0, 0, 0);
        O[nt] = __builtin_amdgcn_mfma_f32_16x16x32_bf16(pa1, vb1, O[nt], 0, 0, 0);
    }
    O[4] = __builtin_amdgcn_mfma_f32_16x16x32_bf16(pa0, ones, O[4], 0, 0, 0);
    O[4] = __builtin_amdgcn_mfma_f32_16x16x32_bf16(pa1, ones, O[4], 0, 0, 0);

    // flush partials to this block's private slab slot (plain stores)
    float* slab = slabs + (size_t)(b * NSLOT + s) * 64 * ACCW;
    const int rl = wv * 16 + quad * 4;
    #pragma unroll
    for (int nt = 0; nt < 4; nt++)
        #pragma unroll
        for (int r = 0; r < 4; r++)
            slab[(size_t)(rl + r) * ACCW + nt * 16 + l16] = O[nt][r];
    if (l16 == 0) {
        #pragma unroll
        for (int r = 0; r < 4; r++)
            slab[(size_t)(rl + r) * ACCW + 64] = O[4][r];
    }
}

// ---------------- K4: reduce slabs + normalize ----------------
__global__ __launch_bounds__(256) void reduce_norm(
    const float* __restrict__ slabs, float* __restrict__ out)
{
    int idx = blockIdx.x * 256 + threadIdx.x;   // 262144 = 16384 rows * 16 float4
    int row = idx >> 4, c4 = (idx & 15) * 4;
    int b = row >> 12, qt = (row >> 6) & 63, r64 = row & 63;
    int a = qt >> 3, nc = a + 1;
    int base = 4 * a * (a + 1) + (qt & 7) * nc;    // first slot of this qt

    const float* sl = slabs + ((size_t)(b * NSLOT + base) * 64 + r64) * ACCW;
    float4 o = make_float4(0.f, 0.f, 0.f, 0.f);
    float l = 0.f;
    for (int i = 0; i < nc; i++) {
        float4 v = *(const float4*)&sl[c4];
        o.x += v.x; o.y += v.y; o.z += v.z; o.w += v.w;
        l += sl[64];
        sl += (size_t)64 * ACCW;
    }
    float inv = 1.f / l;
    *(float4*)&out[(size_t)row * HDIM + c4] =
        make_float4(o.x * inv, o.y * inv, o.z * inv, o.w * inv);
}

extern "C" void kernel_launch(void* const* d_in, const int* in_sizes, int n_in,
                              void* d_out, int out_size, void* d_ws, size_t ws_size,
                              hipStream_t stream) {
    const float* x  = (const float*)d_in[0];
    const float* Wk = (const float*)d_in[1];
    const float* Wq = (const float*)d_in[2];
    const float* Wv = (const float*)d_in[3];
    float* out = (float*)d_out;

    unsigned short* wtg = (unsigned short*)d_ws;        // [192][1024] bf16
    unsigned short* kg  = wtg + 196608;                 // [BT][64] bf16
    unsigned short* qg  = kg + (size_t)BT * HDIM;       // [BT][64] bf16 (q/8)
    unsigned short* vtg = qg + (size_t)BT * HDIM;       // [4][64][4096] bf16
    float* slabs = (float*)(vtg + (size_t)4 * HDIM * TDIM); // [4*288][64][68]

    wtrans<<<768, 256, 0, stream>>>(Wk, Wq, Wv, wtg);
    qkv_proj<<<BT / 32, 256, 0, stream>>>(x, wtg, kg, qg, vtg);
    attn<<<4 * NSLOT, 256, 0, stream>>>(qg, kg, vtg, slabs);
    reduce_norm<<<BT * HDIM / (4 * 256), 256, 0, stream>>>(slabs, out);
}

// Round 13
// 138.323 us; speedup vs baseline: 1.1068x; 1.1068x over previous
//
#include <hip/hip_runtime.h>
#include <math.h>

// B=4, T=4096, C=1024, H=64. fp32 in/out, bf16 MFMA internally.
// SESSION-BEST configuration (round 7, measured 138.4 us) restored verbatim.
// K1 wtrans: W (C,H) fp32 -> WT bf16 [192][1024].
// K2 qkv_proj: 512 thr, K-step 64, [72]-short LDS rows, single-barrier dbuf,
//              8-deep x register ring; WT 1-iter ahead.
// K3 attn: SOFTWARE-PIPELINED flash attention. Per iteration: stage(kt+1) ->
//          barrier -> QK(kt+1) MFMA -> PV(kt) MFMA (18 MFMA fused on the
//          matrix pipe) -> softmax(kt+1) on VALU/trans (its QK dependence is
//          hidden under PV) -> barrier. Only pa (8 VGPR) carried across iters.
//          Swapped mfma(K,Q); in-register P transpose via cvt_pk_bf16 +
//          permlane32/16_swap; l=sum(p) via register-constant ones fragment;
//          plain-store partials to private slab [slot][64][68].
// K4 reduce_norm: per row, sum ceil((qt+1)/8) slabs, out = O_sum / l_sum.

#define BT   16384
#define TDIM 4096
#define CDIM 1024
#define HDIM 64
#define ACCW 68           // slab row stride (floats); col 64 holds l
#define NSLOT 288         // chunk slots per batch (chunk = 8 kv-tiles)

typedef __attribute__((ext_vector_type(8))) short bf16x8;
typedef __attribute__((ext_vector_type(4))) float f32x4;
typedef __attribute__((ext_vector_type(8))) unsigned short us8;
typedef __attribute__((ext_vector_type(4))) unsigned short us4;

static __device__ __forceinline__ unsigned short f2bf(float f) {
    unsigned int u = __float_as_uint(f);
    u += 0x7fffu + ((u >> 16) & 1u);
    return (unsigned short)(u >> 16);
}

// Chained lane-swap: after pswap(x,y),
//   x = [X(q0), X(q2), Y(q0), Y(q2)] per quad, y = [X(q1), X(q3), Y(q1), Y(q3)]
// = A-frag words w / w+2 when X=c[st_lo][h], Y=c[st_hi][h].
static __device__ __forceinline__ void pswap(unsigned &x, unsigned &y) {
    asm("v_permlane32_swap_b32 %0, %1" : "+v"(x), "+v"(y));
    asm("v_permlane16_swap_b32 %0, %1" : "+v"(x), "+v"(y));
}

// p = exp(sT) (+ diagonal causal mask), packed into the PV A-fragment layout.
static __device__ __forceinline__ void softmax_pack(
    const f32x4 sT[4], bool diag, int qloc, int quad,
    bf16x8 &pa0, bf16x8 &pa1)
{
    float p[4][4];
    if (diag) {
        #pragma unroll
        for (int st = 0; st < 4; st++)
            #pragma unroll
            for (int r = 0; r < 4; r++) {
                int kkloc = st * 16 + quad * 4 + r;
                p[st][r] = (kkloc > qloc) ? 0.f : __expf(sT[st][r]);
            }
    } else {
        #pragma unroll
        for (int st = 0; st < 4; st++)
            #pragma unroll
            for (int r = 0; r < 4; r++)
                p[st][r] = __expf(sT[st][r]);
    }
    unsigned cpk[4][2];
    #pragma unroll
    for (int st = 0; st < 4; st++) {
        asm("v_cvt_pk_bf16_f32 %0, %1, %2"
            : "=v"(cpk[st][0]) : "v"(p[st][0]), "v"(p[st][1]));
        asm("v_cvt_pk_bf16_f32 %0, %1, %2"
            : "=v"(cpk[st][1]) : "v"(p[st][2]), "v"(p[st][3]));
    }
    union { unsigned u[4]; bf16x8 v; } u0, u1;
    unsigned a0 = cpk[0][0], b0 = cpk[1][0]; pswap(a0, b0);
    unsigned a1 = cpk[0][1], b1 = cpk[1][1]; pswap(a1, b1);
    u0.u[0] = a0; u0.u[1] = a1; u0.u[2] = b0; u0.u[3] = b1;
    unsigned a2 = cpk[2][0], b2 = cpk[3][0]; pswap(a2, b2);
    unsigned a3 = cpk[2][1], b3 = cpk[3][1]; pswap(a3, b3);
    u1.u[0] = a2; u1.u[1] = a3; u1.u[2] = b2; u1.u[3] = b3;
    pa0 = u0.v; pa1 = u1.v;
}

// ---------------- K1: W transpose->bf16 ----------------
__global__ __launch_bounds__(256) void wtrans(
    const float* __restrict__ Wk, const float* __restrict__ Wq,
    const float* __restrict__ Wv, unsigned short* __restrict__ wtg)
{
    int idx = blockIdx.x * 256 + threadIdx.x;     // 0..196607
    int mat = idx >> 16;
    int rem = idx & 65535;
    int h = rem >> 10, c = rem & 1023;
    const float* W = (mat == 0) ? Wk : (mat == 1) ? Wq : Wv;
    wtg[idx] = f2bf(W[c * HDIM + h]);             // WT[mat*64+h][c]
}

// ---------------- K2: QKV projection (8-deep x-ring, single-barrier dbuf) ---
__global__ __launch_bounds__(512) void qkv_proj(
    const float* __restrict__ x, const unsigned short* __restrict__ wtg,
    unsigned short* __restrict__ kg, unsigned short* __restrict__ qg,
    unsigned short* __restrict__ vtg)
{
    __shared__ __align__(16) unsigned short xs[2][32][72];
    __shared__ __align__(16) unsigned short wts[2][192][72];   // total 63 KB
    const int t = threadIdx.x;
    const int lane = t & 63, wv = t >> 6, quad = lane >> 4, l16 = lane & 15;
    const int mt = wv >> 2;                  // m-tile 0/1 (16 rows each)
    const int nq = wv & 3;                   // n-quarter: n-tiles nq*3..nq*3+2
    const int row0 = blockIdx.x * 32;

    const int xr = t >> 4, xc4 = (t & 15) * 4;       // x: 1 float4/thread/iter
    const int wn = t >> 3, wc8 = (t & 7) * 8;        // WT: 3 us8/thread/iter

    f32x4 acc3[3];
    #pragma unroll
    for (int i = 0; i < 3; i++) acc3[i] = (f32x4){0.f, 0.f, 0.f, 0.f};

    const size_t xrow = (size_t)(row0 + xr) * CDIM + xc4;

    // deep prefetch: issue 8 x-chunk loads up front (static-indexed ring)
    float4 xq[8];
    #pragma unroll
    for (int c = 0; c < 8; c++)
        xq[c] = *(const float4*)&x[xrow + c * 64];

    // WT chunk 0 regs
    us8 w0 = *(const us8*)&wtg[(size_t)(wn +   0) * CDIM + wc8];
    us8 w1 = *(const us8*)&wtg[(size_t)(wn +  64) * CDIM + wc8];
    us8 w2 = *(const us8*)&wtg[(size_t)(wn + 128) * CDIM + wc8];

    // stage tile 0 -> buf 0 (consumes xq[0]); refill slot 0 with chunk 8
    {
        us4 pk = { f2bf(xq[0].x), f2bf(xq[0].y), f2bf(xq[0].z), f2bf(xq[0].w) };
        *(us4*)&xs[0][xr][xc4] = pk;
        *(us8*)&wts[0][wn +   0][wc8] = w0;
        *(us8*)&wts[0][wn +  64][wc8] = w1;
        *(us8*)&wts[0][wn + 128][wc8] = w2;
    }
    xq[0] = *(const float4*)&x[xrow + 8 * 64];
    w0 = *(const us8*)&wtg[(size_t)(wn +   0) * CDIM + 64 + wc8];
    w1 = *(const us8*)&wtg[(size_t)(wn +  64) * CDIM + 64 + wc8];
    w2 = *(const us8*)&wtg[(size_t)(wn + 128) * CDIM + 64 + wc8];
    __syncthreads();

    #pragma unroll
    for (int it = 0; it < 16; it++) {
        const int buf = it & 1;
        if (it + 1 < 16) {
            // stage tile it+1 from ring slot (it+1)&7 and WT regs
            const int sl = (it + 1) & 7;
            us4 pk = { f2bf(xq[sl].x), f2bf(xq[sl].y),
                       f2bf(xq[sl].z), f2bf(xq[sl].w) };
            *(us4*)&xs[buf ^ 1][xr][xc4] = pk;
            *(us8*)&wts[buf ^ 1][wn +   0][wc8] = w0;
            *(us8*)&wts[buf ^ 1][wn +  64][wc8] = w1;
            *(us8*)&wts[buf ^ 1][wn + 128][wc8] = w2;
            if (it + 9 < 16)
                xq[sl] = *(const float4*)&x[xrow + (it + 9) * 64];
            if (it + 2 < 16) {
                int nc = (it + 2) * 64;
                w0 = *(const us8*)&wtg[(size_t)(wn +   0) * CDIM + nc + wc8];
                w1 = *(const us8*)&wtg[(size_t)(wn +  64) * CDIM + nc + wc8];
                w2 = *(const us8*)&wtg[(size_t)(wn + 128) * CDIM + nc + wc8];
            }
        }
        bf16x8 a0 = *(const bf16x8*)&xs[buf][mt * 16 + l16][quad * 8];
        bf16x8 a1 = *(const bf16x8*)&xs[buf][mt * 16 + l16][32 + quad * 8];
        #pragma unroll
        for (int j = 0; j < 3; j++) {
            int nt = nq * 3 + j;
            bf16x8 b0 = *(const bf16x8*)&wts[buf][nt * 16 + l16][quad * 8];
            bf16x8 b1 = *(const bf16x8*)&wts[buf][nt * 16 + l16][32 + quad * 8];
            acc3[j] = __builtin_amdgcn_mfma_f32_16x16x32_bf16(a0, b0, acc3[j], 0, 0, 0);
            acc3[j] = __builtin_amdgcn_mfma_f32_16x16x32_bf16(a1, b1, acc3[j], 0, 0, 0);
        }
        __syncthreads();
    }

    const int mrow = row0 + mt * 16 + quad * 4;
    #pragma unroll
    for (int j = 0; j < 3; j++) {
        int nt = nq * 3 + j;
        int mat = nt >> 2;
        int col = (nt & 3) * 16 + l16;
        if (mat == 2) {
            // V: 4 regs are 4 consecutive t at fixed h -> contiguous in vtg
            int bb = mrow >> 12, tr = mrow & 4095;   // rows never cross batch
            us4 pv = { f2bf(acc3[j][0]), f2bf(acc3[j][1]),
                       f2bf(acc3[j][2]), f2bf(acc3[j][3]) };
            *(us4*)&vtg[((size_t)(bb * HDIM + col) << 12) + tr] = pv;
        } else {
            // Q is pre-scaled by 1/8 (exact power-of-2 in bf16)
            float s = (mat == 1) ? 0.125f : 1.0f;
            unsigned short* dst = (mat == 0) ? kg : qg;
            #pragma unroll
            for (int reg = 0; reg < 4; reg++)
                dst[(size_t)(mrow + reg) * HDIM + col] = f2bf(acc3[j][reg] * s);
        }
    }
}

// ---------------- K3: software-pipelined flash attention ----------
// slot layout per batch (chunk = 8 tiles): group a = qt>>3 has (a+1) chunks
// per qt; group a starts at slot 4a(a+1); qt's slots: base + (qt&7)*(a+1).
__global__ __launch_bounds__(256) void attn(
    const unsigned short* __restrict__ qg, const unsigned short* __restrict__ kg,
    const unsigned short* __restrict__ vtg, float* __restrict__ slabs)
{
    __shared__ __align__(16) unsigned short Ks[2][64][72];
    __shared__ __align__(16) unsigned short Vt[2][64][72];    // 36 KB total

    const int t = threadIdx.x;
    const int lane = t & 63, wv = t >> 6, quad = lane >> 4, l16 = lane & 15;

    const int b = blockIdx.x / NSLOT;
    const int s = blockIdx.x - b * NSLOT;
    int a;
    if      (s < 8)   a = 0;
    else if (s < 24)  a = 1;
    else if (s < 48)  a = 2;
    else if (s < 80)  a = 3;
    else if (s < 120) a = 4;
    else if (s < 168) a = 5;
    else if (s < 224) a = 6;
    else              a = 7;
    const int u  = s - 4 * a * (a + 1);
    const int qt = a * 8 + u / (a + 1);
    const int c  = u % (a + 1);

    const size_t bbase = (size_t)b * TDIM;
    const int Q0 = qt * 64;
    const int kt0 = c * 8;
    const int kt1 = (kt0 + 7 < qt) ? kt0 + 7 : qt;

    // Q fragments (B-operand of swapped QK^T: n=l16 is the q-row)
    const int qrow = Q0 + wv * 16 + l16;
    const bf16x8 qa0 = *(const bf16x8*)&qg[(bbase + qrow) * HDIM + quad * 8];
    const bf16x8 qa1 = *(const bf16x8*)&qg[(bbase + qrow) * HDIM + 32 + quad * 8];

    // l-row B-fragment: register constant (col 0 of virtual ones-row)
    const short onev = (l16 == 0) ? (short)0x3F80 : (short)0;
    const bf16x8 ones = { onev, onev, onev, onev, onev, onev, onev, onev };

    f32x4 O[5];
    #pragma unroll
    for (int i = 0; i < 5; i++) O[i] = (f32x4){0.f, 0.f, 0.f, 0.f};

    const int fr = t >> 3, fc = (t & 7) * 8;

    // prologue: tile kt0 -> buf 0; preload tile kt0+1 into regs
    us8 kr0 = *(const us8*)&kg[(bbase + kt0 * 64 + fr) * HDIM + fc];
    us8 kr1 = *(const us8*)&kg[(bbase + kt0 * 64 + fr + 32) * HDIM + fc];
    us8 vr0 = *(const us8*)&vtg[((size_t)(b * HDIM + fr) << 12) + kt0 * 64 + fc];
    us8 vr1 = *(const us8*)&vtg[((size_t)(b * HDIM + fr + 32) << 12) + kt0 * 64 + fc];
    *(us8*)&Ks[0][fr][fc] = kr0;
    *(us8*)&Ks[0][fr + 32][fc] = kr1;
    *(us8*)&Vt[0][fr][fc] = vr0;
    *(us8*)&Vt[0][fr + 32][fc] = vr1;
    if (kt0 < kt1) {
        int kn = kt0 + 1;
        kr0 = *(const us8*)&kg[(bbase + kn * 64 + fr) * HDIM + fc];
        kr1 = *(const us8*)&kg[(bbase + kn * 64 + fr + 32) * HDIM + fc];
        vr0 = *(const us8*)&vtg[((size_t)(b * HDIM + fr) << 12) + kn * 64 + fc];
        vr1 = *(const us8*)&vtg[((size_t)(b * HDIM + fr + 32) << 12) + kn * 64 + fc];
    }
    __syncthreads();

    const int qloc = wv * 16 + l16;        // this lane's q row, Q-tile-local

    // prologue compute: QK(kt0) + softmax(kt0) -> pa
    bf16x8 pa0, pa1;
    {
        f32x4 sT[4];
        #pragma unroll
        for (int st = 0; st < 4; st++) {
            bf16x8 kb0 = *(const bf16x8*)&Ks[0][st * 16 + l16][quad * 8];
            bf16x8 kb1 = *(const bf16x8*)&Ks[0][st * 16 + l16][32 + quad * 8];
            f32x4 z = (f32x4){0.f, 0.f, 0.f, 0.f};
            z = __builtin_amdgcn_mfma_f32_16x16x32_bf16(kb0, qa0, z, 0, 0, 0);
            z = __builtin_amdgcn_mfma_f32_16x16x32_bf16(kb1, qa1, z, 0, 0, 0);
            sT[st] = z;
        }
        softmax_pack(sT, kt0 == qt, qloc, quad, pa0, pa1);
    }

    int buf = 0;
    for (int kt = kt0; kt < kt1; ++kt) {
        // stage tile kt+1 (in regs) into buf^1; issue preload of kt+2
        *(us8*)&Ks[buf ^ 1][fr][fc] = kr0;
        *(us8*)&Ks[buf ^ 1][fr + 32][fc] = kr1;
        *(us8*)&Vt[buf ^ 1][fr][fc] = vr0;
        *(us8*)&Vt[buf ^ 1][fr + 32][fc] = vr1;
        if (kt + 2 <= kt1) {
            int kn = kt + 2;
            kr0 = *(const us8*)&kg[(bbase + kn * 64 + fr) * HDIM + fc];
            kr1 = *(const us8*)&kg[(bbase + kn * 64 + fr + 32) * HDIM + fc];
            vr0 = *(const us8*)&vtg[((size_t)(b * HDIM + fr) << 12) + kn * 64 + fc];
            vr1 = *(const us8*)&vtg[((size_t)(b * HDIM + fr + 32) << 12) + kn * 64 + fc];
        }
        __syncthreads();

        // QK(kt+1) from Ks[buf^1], then PV(kt) from Vt[buf]: 18 MFMA fused.
        __builtin_amdgcn_s_setprio(1);
        f32x4 sT[4];
        #pragma unroll
        for (int st = 0; st < 4; st++) {
            bf16x8 kb0 = *(const bf16x8*)&Ks[buf ^ 1][st * 16 + l16][quad * 8];
            bf16x8 kb1 = *(const bf16x8*)&Ks[buf ^ 1][st * 16 + l16][32 + quad * 8];
            f32x4 z = (f32x4){0.f, 0.f, 0.f, 0.f};
            z = __builtin_amdgcn_mfma_f32_16x16x32_bf16(kb0, qa0, z, 0, 0, 0);
            z = __builtin_amdgcn_mfma_f32_16x16x32_bf16(kb1, qa1, z, 0, 0, 0);
            sT[st] = z;
        }
        #pragma unroll
        for (int nt = 0; nt < 4; nt++) {
            bf16x8 vb0 = *(const bf16x8*)&Vt[buf][nt * 16 + l16][quad * 8];
            bf16x8 vb1 = *(const bf16x8*)&Vt[buf][nt * 16 + l16][32 + quad * 8];
            O[nt] = __builtin_amdgcn_mfma_f32_16x16x32_bf16(pa0, vb0, O[nt], 0, 0, 0);
            O[nt] = __builtin_amdgcn_mfma_f32_16x16x32_bf16(pa1, vb1, O[nt], 0, 0, 0);
        }
        O[4] = __builtin_amdgcn_mfma_f32_16x16x32_bf16(pa0, ones, O[4], 0, 0, 0);
        O[4] = __builtin_amdgcn_mfma_f32_16x16x32_bf16(pa1, ones, O[4], 0, 0, 0);
        __builtin_amdgcn_s_setprio(0);

        // softmax(kt+1): its QK dependence drains while PV occupies the pipe
        softmax_pack(sT, (kt + 1) == qt, qloc, quad, pa0, pa1);

        __syncthreads();
        buf ^= 1;
    }

    // epilogue: PV(kt1) from Vt[buf]
    #pragma unroll
    for (int nt = 0; nt < 4; nt++) {
        bf16x8 vb0 = *(const bf16x8*)&Vt[buf][nt * 16 + l16][quad * 8];
        bf16x8 vb1 = *(const bf16x8*)&Vt[buf][nt * 16 + l16][32 + quad * 8];
        O[nt] = __builtin_amdgcn_mfma_f32_16x16x32_bf16(pa0, vb0, O[nt], 0, 0, 0);
        O[nt] = __builtin_amdgcn_mfma_f32_16x16x32_bf16(pa1, vb1, O[nt], 0, 0, 0);
    }
    O[4] = __builtin_amdgcn_mfma_f32_16x16x32_bf16(pa0, ones, O[4], 0, 0, 0);
    O[4] = __builtin_amdgcn_mfma_f32_16x16x32_bf16(pa1, ones, O[4], 0, 0, 0);

    // flush partials to this block's private slab slot (plain stores)
    float* slab = slabs + (size_t)(b * NSLOT + s) * 64 * ACCW;
    const int rl = wv * 16 + quad * 4;
    #pragma unroll
    for (int nt = 0; nt < 4; nt++)
        #pragma unroll
        for (int r = 0; r < 4; r++)
            slab[(size_t)(rl + r) * ACCW + nt * 16 + l16] = O[nt][r];
    if (l16 == 0) {
        #pragma unroll
        for (int r = 0; r < 4; r++)
            slab[(size_t)(rl + r) * ACCW + 64] = O[4][r];
    }
}

// ---------------- K4: reduce slabs + normalize ----------------
__global__ __launch_bounds__(256) void reduce_norm(
    const float* __restrict__ slabs, float* __restrict__ out)
{
    int idx = blockIdx.x * 256 + threadIdx.x;   // 262144 = 16384 rows * 16 float4
    int row = idx >> 4, c4 = (idx & 15) * 4;
    int b = row >> 12, qt = (row >> 6) & 63, r64 = row & 63;
    int a = qt >> 3, nc = a + 1;
    int base = 4 * a * (a + 1) + (qt & 7) * nc;    // first slot of this qt

    const float* sl = slabs + ((size_t)(b * NSLOT + base) * 64 + r64) * ACCW;
    float4 o = make_float4(0.f, 0.f, 0.f, 0.f);
    float l = 0.f;
    for (int i = 0; i < nc; i++) {
        float4 v = *(const float4*)&sl[c4];
        o.x += v.x; o.y += v.y; o.z += v.z; o.w += v.w;
        l += sl[64];
        sl += (size_t)64 * ACCW;
    }
    float inv = 1.f / l;
    *(float4*)&out[(size_t)row * HDIM + c4] =
        make_float4(o.x * inv, o.y * inv, o.z * inv, o.w * inv);
}

extern "C" void kernel_launch(void* const* d_in, const int* in_sizes, int n_in,
                              void* d_out, int out_size, void* d_ws, size_t ws_size,
                              hipStream_t stream) {
    const float* x  = (const float*)d_in[0];
    const float* Wk = (const float*)d_in[1];
    const float* Wq = (const float*)d_in[2];
    const float* Wv = (const float*)d_in[3];
    float* out = (float*)d_out;

    unsigned short* wtg = (unsigned short*)d_ws;        // [192][1024] bf16
    unsigned short* kg  = wtg + 196608;                 // [BT][64] bf16
    unsigned short* qg  = kg + (size_t)BT * HDIM;       // [BT][64] bf16 (q/8)
    unsigned short* vtg = qg + (size_t)BT * HDIM;       // [4][64][4096] bf16
    float* slabs = (float*)(vtg + (size_t)4 * HDIM * TDIM); // [4*288][64][68]

    wtrans<<<768, 256, 0, stream>>>(Wk, Wq, Wv, wtg);
    qkv_proj<<<BT / 32, 512, 0, stream>>>(x, wtg, kg, qg, vtg);
    attn<<<4 * NSLOT, 256, 0, stream>>>(qg, kg, vtg, slabs);
    reduce_norm<<<BT * HDIM / (4 * 256), 256, 0, stream>>>(slabs, out);
}